// Round 41
// baseline (87.756 us; speedup 1.0000x reference)
//
#include <hip/hip_runtime.h>
#include <math.h>

#define EPSF    1e-8f
#define RADIUSF 0.1f
#define BN_EPSF 1e-5f

constexpr int Kn  = 33;     // neighbors incl. self slot
constexpr int PPB = 8;      // points per block
constexpr int NTHREADS = PPB * 32;   // 256
constexpr int Nn = 4096;
constexpr int NPTS = 8 * Nn;

typedef _Float16 f16x2 __attribute__((ext_vector_type(2)));
union F16Pack { f16x2 h; unsigned u; };

// ws layout (4B units): [0:32) s1 | [32:64) t1 | [64:128) s2 | [128:192) t2
//                       [192:384) w1 packed f16x2 | [384:1408) w2 packed f16x2
constexpr int WS_S1 = 0, WS_T1 = 32, WS_S2 = 64, WS_T2 = 128;
constexpr int WS_W1 = 192, WS_W2 = 384;

__global__ void prep(const float* __restrict__ w1, const float* __restrict__ g1,
                     const float* __restrict__ b1, const float* __restrict__ m1,
                     const float* __restrict__ v1, const float* __restrict__ w2,
                     const float* __restrict__ g2, const float* __restrict__ b2,
                     const float* __restrict__ m2, const float* __restrict__ v2,
                     float* __restrict__ wsf)
{
    const int tid = threadIdx.x;           // 1 block x 256 threads
    unsigned* wsu = (unsigned*)wsf;
    if (tid < 32) {
        float s = g1[tid] / sqrtf(v1[tid] + BN_EPSF);
        wsf[WS_S1 + tid] = s;
        wsf[WS_T1 + tid] = b1[tid] - m1[tid] * s;
    }
    if (tid < 64) {
        float s = g2[tid] / sqrtf(v2[tid] + BN_EPSF);
        wsf[WS_S2 + tid] = s;
        wsf[WS_T2 + tid] = b2[tid] - m2[tid] * s;
    }
    for (int i = tid; i < 192; i += 256) {   // w1: 384 floats -> 192 pairs
        F16Pack cv;
        cv.h[0] = (_Float16)w1[2 * i];
        cv.h[1] = (_Float16)w1[2 * i + 1];
        wsu[WS_W1 + i] = cv.u;
    }
    for (int i = tid; i < 1024; i += 256) {  // w2: 2048 floats -> 1024 pairs
        F16Pack cv;
        cv.h[0] = (_Float16)w2[2 * i];
        cv.h[1] = (_Float16)w2[2 * i + 1];
        wsu[WS_W2 + i] = cv.u;
    }
}

// channel-splitting butterfly max: after all 5 steps lane t owns channel t
template<int Mm, int H>
__device__ __forceinline__ void rstep(float* acc, int t) {
    const bool up = (t & Mm) != 0;
#pragma unroll
    for (int j = 0; j < H; ++j) {
        float snd = up ? acc[j] : acc[j + H];   // the half I discard
        float oth = __shfl_xor(snd, Mm);
        float kep = up ? acc[j + H] : acc[j];
        acc[j] = fmaxf(kep, oth);
    }
}

__global__ __launch_bounds__(NTHREADS)
void rri_fused(const float* __restrict__ xyz,
               const float* __restrict__ mask,
               const float* __restrict__ wsf,
               float* __restrict__ out)
{
    __shared__ float    xyz_s[PPB][Kn * 3];
    __shared__ float    mask_s[PPB][Kn];
    __shared__ unsigned w2_s[1024];         // conv2 weights, f16x2 pairs (4 KB)
    __shared__ float    res[64][PPB + 1];   // +1 pad

    const unsigned* wsu = (const unsigned*)wsf;
    const int tid = threadIdx.x;
    const int pt  = tid >> 5;   // point within block
    const int t   = tid & 31;   // lane within point = neighbor index - 1
    const int p0  = blockIdx.x * PPB;

    // ---- stage xyz / mask / conv2 weights (contiguous, coalesced) ----
    {
        const float* xg = xyz + (size_t)p0 * (Kn * 3);
        for (int i = tid; i < PPB * Kn * 3; i += NTHREADS)
            (&xyz_s[0][0])[i] = xg[i];
        const float* mg = mask + (size_t)p0 * Kn;
        for (int i = tid; i < PPB * Kn; i += NTHREADS)
            (&mask_s[0][0])[i] = mg[i];
#pragma unroll
        for (int i = 0; i < 4; ++i)
            w2_s[i * 256 + tid] = wsu[WS_W2 + i * 256 + tid];
    }
    __syncthreads();

    const float* P = xyz_s[pt];
    const float* M = mask_s[pt];

    const float rx = P[0], ry = P[1], rz = P[2];
    const float gx = P[(t + 1) * 3 + 0], gy = P[(t + 1) * 3 + 1], gz = P[(t + 1) * 3 + 2];

    // ---- masked distance row-sum for i = t+1 ----
    // per-pair d2 in f32 exactly like the reference; K-sum in f64 (exact)
    double dsum;
    {
        double s = 0.0;
#pragma unroll
        for (int j = 0; j < Kn; ++j) {
            float dx = gx - P[j * 3 + 0];
            float dy = gy - P[j * 3 + 1];
            float dz = gz - P[j * 3 + 2];
            float d2 = dx * dx + dy * dy + dz * dz;
            s += (double)(d2 * M[j]);
        }
        dsum = s + (double)((1.0f - M[t + 1]) * 10000.0f);
    }

    // ---- butterfly argmin over the point's 32 lanes (first-index tie-break)
    int cidx = t + 1;
    {
        double dv = dsum;
#pragma unroll
        for (int m = 16; m >= 1; m >>= 1) {
            double od = __shfl_xor(dv, m);
            int    oi = __shfl_xor(cidx, m);
            if (od < dv || (od == dv && oi < cidx)) { dv = od; cidx = oi; }
        }
    }
    const float cx = P[cidx * 3 + 0], cy = P[cidx * 3 + 1], cz = P[cidx * 3 + 2];

    // ---- center features (identical across the 32 lanes of a point) ----
    const float rnorm = sqrtf(rx * rx + ry * ry + rz * rz);
    const float invr  = 1.0f / (rnorm + EPSF);
    const float ux = rx * invr, uy = ry * invr, uz = rz * invr;
    const float ix = RADIUSF * ux + rx, iy = RADIUSF * uy + ry, iz = RADIUSF * uz + rz;

    const float crx = rx - cx, cry = ry - cy, crz = rz - cz;
    const float crd = sqrtf(crx * crx + cry * cry + crz * crz);
    const float icr = 1.0f / (crd + EPSF);
    const float crnx = crx * icr, crny = cry * icr, crnz = crz * icr;

    const float cix = ix - cx, ciy = iy - cy, ciz = iz - cz;
    const float cid = sqrtf(cix * cix + ciy * ciy + ciz * ciz);
    const float ici = 1.0f / (cid + EPSF);
    const float cinx = cix * ici, ciny = ciy * ici, cinz = ciz * ici;

    const float a_rci = crnx * cinx + crny * ciny + crnz * cinz;

    const float irx = rx - ix, iry = ry - iy, irz = rz - iz;
    const float ird = sqrtf(irx * irx + iry * iry + irz * irz);
    const float iir = 1.0f / (ird + EPSF);
    const float irnx = irx * iir, irny = iry * iir, irnz = irz * iir;

    const float icx = cx - ix, icy = cy - iy, icz = cz - iz;
    const float icd = sqrtf(icx * icx + icy * icy + icz * icz);
    const float iic = 1.0f / (icd + EPSF);
    const float icnx = icx * iic, icny = icy * iic, icnz = icz * iic;

    const float a_ric = irnx * icnx + irny * icny + irnz * icnz;

    // reference plane normal: cross(r - i, c - r), normalized
    const float e1x = rx - ix, e1y = ry - iy, e1z = rz - iz;
    const float e2x = cx - rx, e2y = cy - ry, e2z = cz - rz;
    float rnx = e1y * e2z - e1z * e2y;
    float rny = e1z * e2x - e1x * e2z;
    float rnz = e1x * e2y - e1y * e2x;
    const float rnl  = sqrtf(rnx * rnx + rny * rny + rnz * rnz);
    const float irnl = 1.0f / (rnl + EPSF);
    rnx *= irnl; rny *= irnl; rnz *= irnl;

    // ---- per-neighbor features ----
    const float ncx = cx - gx, ncy = cy - gy, ncz = cz - gz;
    const float ncd = sqrtf(ncx * ncx + ncy * ncy + ncz * ncz);
    const float inc = 1.0f / (ncd + EPSF);
    const float ncnx = ncx * inc, ncny = ncy * inc, ncnz = ncz * inc;

    const float nrx = rx - gx, nry = ry - gy, nrz = rz - gz;
    const float nrd = sqrtf(nrx * nrx + nry * nry + nrz * nrz);
    const float inr = 1.0f / (nrd + EPSF);
    const float nrnx = nrx * inr, nrny = nry * inr, nrnz = nrz * inr;

    const float nivx = ix - gx, nivy = iy - gy, nivz = iz - gz;
    const float nid = sqrtf(nivx * nivx + nivy * nivy + nivz * nivz);
    const float ini = 1.0f / (nid + EPSF);
    const float ninx = nivx * ini, niny = nivy * ini, ninz = nivz * ini;

    const float ang_cnr = ncnx * nrnx + ncny * nrny + ncnz * nrnz;
    const float ang_rni = nrnx * ninx + nrny * niny + nrnz * ninz;
    const float ang_inc = ninx * ncnx + niny * ncny + ninz * ncnz;

    // neighbor plane normal: cross(r - i, g - r), normalized
    const float f2x = gx - rx, f2y = gy - ry, f2z = gz - rz;
    float qnx = e1y * f2z - e1z * f2y;
    float qny = e1z * f2x - e1x * f2z;
    float qnz = e1x * f2y - e1y * f2x;
    const float qnl = sqrtf(qnx * qnx + qny * qny + qnz * qnz);
    const float iqn = 1.0f / (qnl + EPSF);
    qnx *= iqn; qny *= iqn; qnz *= iqn;

    float dt = rnx * qnx + rny * qny + rnz * qnz;
    dt = fminf(fmaxf(dt, -1.0f), 1.0f);
    // angle = cos(pad/4) - sin(pad/4) - 0.75 via double half-angle (no acosf)
    const float pss = rnx * f2x + rny * f2y + rnz * f2z;   // ref_n . (g - r)
    const float sgn = (pss > 0.0f) ? 1.0f : ((pss < 0.0f) ? -1.0f : 0.0f);
    const float c2  = sqrtf(fmaxf(0.5f * (1.0f + dt), 0.0f));
    const float c4  = sqrtf(fmaxf(0.5f * (1.0f + c2), 0.0f));
    const float s4  = sqrtf(fmaxf(0.5f * (1.0f - c2), 0.0f));
    const float ceff = (sgn == 0.0f) ? 1.0f : c4;          // pad==0 when sign==0
    const float angle = ceff - sgn * s4 - 0.75f;

    // ---- pack the 12 features into 6 f16x2 ----
    F16Pack fp[6];
    fp[0].h[0] = (_Float16)rnorm;   fp[0].h[1] = (_Float16)crd;
    fp[1].h[0] = (_Float16)cid;     fp[1].h[1] = (_Float16)a_rci;
    fp[2].h[0] = (_Float16)a_ric;   fp[2].h[1] = (_Float16)ncd;
    fp[3].h[0] = (_Float16)nrd;     fp[3].h[1] = (_Float16)nid;
    fp[4].h[0] = (_Float16)ang_cnr; fp[4].h[1] = (_Float16)ang_rni;
    fp[5].h[0] = (_Float16)ang_inc; fp[5].h[1] = (_Float16)angle;

    // ---- conv1 12->32 + BN + ReLU via fdot2 (6 per channel) ----
    float h1[32];
#pragma unroll
    for (int o = 0; o < 32; ++o) {
        float a = 0.0f;
#pragma unroll
        for (int k = 0; k < 6; ++k) {
            F16Pack wv; wv.u = wsu[WS_W1 + o * 6 + k];   // uniform -> s_load
            a = __builtin_amdgcn_fdot2(wv.h, fp[k].h, a, false);
        }
        h1[o] = fmaxf(fmaf(a, wsf[WS_S1 + o], wsf[WS_T1 + o]), 0.0f);
    }

    // ---- pack h1 into 16 f16x2 ----
    F16Pack hp[16];
#pragma unroll
    for (int k = 0; k < 16; ++k) {
        hp[k].h[0] = (_Float16)h1[2 * k];
        hp[k].h[1] = (_Float16)h1[2 * k + 1];
    }

    // ---- conv2 32->64 + BN + ReLU via fdot2 (weights from LDS) ----
#pragma unroll
    for (int half = 0; half < 2; ++half) {
        float acc[32];
#pragma unroll
        for (int o = 0; o < 32; ++o) {
            const int oo = half * 32 + o;
            const unsigned* wrow = &w2_s[oo * 16];
            float a = 0.0f;
#pragma unroll
            for (int k = 0; k < 16; ++k) {
                F16Pack wv; wv.u = wrow[k];
                a = __builtin_amdgcn_fdot2(wv.h, hp[k].h, a, false);
            }
            acc[o] = fmaxf(fmaf(a, wsf[WS_S2 + oo], wsf[WS_T2 + oo]), 0.0f);
        }
        rstep<16, 16>(acc, t);
        rstep<8, 8>(acc, t);
        rstep<4, 4>(acc, t);
        rstep<2, 2>(acc, t);
        rstep<1, 1>(acc, t);
        res[half * 32 + t][pt] = acc[0];
    }
    __syncthreads();

    // ---- coalesced-ish output: out[b][o][n], 8 consecutive n per block ----
    const int b  = p0 >> 12;          // / 4096
    const int n0 = p0 & (Nn - 1);
    float* ob = out + (size_t)b * 64 * Nn + n0;
    for (int i2 = tid; i2 < 64 * PPB; i2 += NTHREADS) {
        int o = i2 >> 3, q = i2 & 7;
        ob[(size_t)o * Nn + q] = res[o][q];
    }
}

extern "C" void kernel_launch(void* const* d_in, const int* in_sizes, int n_in,
                              void* d_out, int out_size, void* d_ws, size_t ws_size,
                              hipStream_t stream) {
    const float* xyz  = (const float*)d_in[0];
    const float* mask = (const float*)d_in[1];
    const float* w1   = (const float*)d_in[2];
    const float* g1   = (const float*)d_in[3];
    const float* b1   = (const float*)d_in[4];
    const float* m1   = (const float*)d_in[5];
    const float* v1   = (const float*)d_in[6];
    const float* w2   = (const float*)d_in[7];
    const float* g2   = (const float*)d_in[8];
    const float* b2   = (const float*)d_in[9];
    const float* m2   = (const float*)d_in[10];
    const float* v2   = (const float*)d_in[11];
    float* out = (float*)d_out;
    float* wsf = (float*)d_ws;

    prep<<<1, 256, 0, stream>>>(w1, g1, b1, m1, v1, w2, g2, b2, m2, v2, wsf);
    rri_fused<<<dim3(NPTS / PPB), NTHREADS, 0, stream>>>(xyz, mask, wsf, out);
}

// Round 42
// 82.688 us; speedup vs baseline: 1.0613x; 1.0613x over previous
//
#include <hip/hip_runtime.h>
#include <math.h>

#define EPSF    1e-8f
#define RADIUSF 0.1f
#define BN_EPSF 1e-5f

constexpr int Kn  = 33;     // neighbors incl. self slot
constexpr int PPB = 8;      // points per block
constexpr int NTHREADS = PPB * 32;   // 256
constexpr int Nn = 4096;
constexpr int NPTS = 8 * Nn;

typedef _Float16 f16x2 __attribute__((ext_vector_type(2)));
union F16Pack { f16x2 h; unsigned u; };

// ws layout (4B units): [0:32) s1 | [32:64) t1 | [64:128) s2 | [128:192) t2
//                       [192:384) w1 packed f16x2 | [384:1408) w2 packed f16x2
constexpr int WS_S1 = 0, WS_T1 = 32, WS_S2 = 64, WS_T2 = 128;
constexpr int WS_W1 = 192, WS_W2 = 384;

__global__ void prep(const float* __restrict__ w1, const float* __restrict__ g1,
                     const float* __restrict__ b1, const float* __restrict__ m1,
                     const float* __restrict__ v1, const float* __restrict__ w2,
                     const float* __restrict__ g2, const float* __restrict__ b2,
                     const float* __restrict__ m2, const float* __restrict__ v2,
                     float* __restrict__ wsf)
{
    const int tid = threadIdx.x;           // 1 block x 256 threads
    unsigned* wsu = (unsigned*)wsf;
    if (tid < 32) {
        float s = g1[tid] / sqrtf(v1[tid] + BN_EPSF);
        wsf[WS_S1 + tid] = s;
        wsf[WS_T1 + tid] = b1[tid] - m1[tid] * s;
    }
    if (tid < 64) {
        float s = g2[tid] / sqrtf(v2[tid] + BN_EPSF);
        wsf[WS_S2 + tid] = s;
        wsf[WS_T2 + tid] = b2[tid] - m2[tid] * s;
    }
    for (int i = tid; i < 192; i += 256) {   // w1: 384 floats -> 192 pairs
        F16Pack cv;
        cv.h[0] = (_Float16)w1[2 * i];
        cv.h[1] = (_Float16)w1[2 * i + 1];
        wsu[WS_W1 + i] = cv.u;
    }
    for (int i = tid; i < 1024; i += 256) {  // w2: 2048 floats -> 1024 pairs
        F16Pack cv;
        cv.h[0] = (_Float16)w2[2 * i];
        cv.h[1] = (_Float16)w2[2 * i + 1];
        wsu[WS_W2 + i] = cv.u;
    }
}

// channel-splitting butterfly max: after all 5 steps lane t owns channel t
template<int Mm, int H>
__device__ __forceinline__ void rstep(float* acc, int t) {
    const bool up = (t & Mm) != 0;
#pragma unroll
    for (int j = 0; j < H; ++j) {
        float snd = up ? acc[j] : acc[j + H];   // the half I discard
        float oth = __shfl_xor(snd, Mm);
        float kep = up ? acc[j + H] : acc[j];
        acc[j] = fmaxf(kep, oth);
    }
}

__global__ void rri_fused(const float* __restrict__ xyz,
                          const float* __restrict__ mask,
                          const float* __restrict__ wsf,
                          float* __restrict__ out)
{
    __shared__ float xyz_s[PPB][Kn * 3];
    __shared__ float mask_s[PPB][Kn];
    __shared__ float res[64][PPB + 1];   // +1 pad

    const unsigned* wsu = (const unsigned*)wsf;
    const int tid = threadIdx.x;
    const int pt  = tid >> 5;   // point within block
    const int t   = tid & 31;   // lane within point = neighbor index - 1
    const int p0  = blockIdx.x * PPB;

    // ---- stage xyz / mask (contiguous, coalesced) ----
    {
        const float* xg = xyz + (size_t)p0 * (Kn * 3);
        for (int i = tid; i < PPB * Kn * 3; i += NTHREADS)
            (&xyz_s[0][0])[i] = xg[i];
        const float* mg = mask + (size_t)p0 * Kn;
        for (int i = tid; i < PPB * Kn; i += NTHREADS)
            (&mask_s[0][0])[i] = mg[i];
    }
    __syncthreads();

    const float* P = xyz_s[pt];
    const float* M = mask_s[pt];

    const float rx = P[0], ry = P[1], rz = P[2];
    const float gx = P[(t + 1) * 3 + 0], gy = P[(t + 1) * 3 + 1], gz = P[(t + 1) * 3 + 2];

    // ---- masked distance row-sum for i = t+1 ----
    // per-pair d2 in f32 exactly like the reference; K-sum in f64 (exact).
    double dsum;
    {
        double s = 0.0;
#pragma unroll
        for (int j = 0; j < Kn; ++j) {
            float dx = gx - P[j * 3 + 0];
            float dy = gy - P[j * 3 + 1];
            float dz = gz - P[j * 3 + 2];
            float d2 = dx * dx + dy * dy + dz * dz;
            s += (double)(d2 * M[j]);
        }
        dsum = s + (double)((1.0f - M[t + 1]) * 10000.0f);
    }

    // ---- butterfly argmin over the point's 32 lanes (first-index tie-break)
    int cidx = t + 1;
    {
        double dv = dsum;
#pragma unroll
        for (int m = 16; m >= 1; m >>= 1) {
            double od = __shfl_xor(dv, m);
            int    oi = __shfl_xor(cidx, m);
            if (od < dv || (od == dv && oi < cidx)) { dv = od; cidx = oi; }
        }
    }
    const float cx = P[cidx * 3 + 0], cy = P[cidx * 3 + 1], cz = P[cidx * 3 + 2];

    // ---- center features (identical across the 32 lanes of a point) ----
    const float rnorm = sqrtf(rx * rx + ry * ry + rz * rz);
    const float invr  = 1.0f / (rnorm + EPSF);
    const float ux = rx * invr, uy = ry * invr, uz = rz * invr;
    const float ix = RADIUSF * ux + rx, iy = RADIUSF * uy + ry, iz = RADIUSF * uz + rz;

    const float crx = rx - cx, cry = ry - cy, crz = rz - cz;
    const float crd = sqrtf(crx * crx + cry * cry + crz * crz);
    const float icr = 1.0f / (crd + EPSF);
    const float crnx = crx * icr, crny = cry * icr, crnz = crz * icr;

    const float cix = ix - cx, ciy = iy - cy, ciz = iz - cz;
    const float cid = sqrtf(cix * cix + ciy * ciy + ciz * ciz);
    const float ici = 1.0f / (cid + EPSF);
    const float cinx = cix * ici, ciny = ciy * ici, cinz = ciz * ici;

    const float a_rci = crnx * cinx + crny * ciny + crnz * cinz;

    const float irx = rx - ix, iry = ry - iy, irz = rz - iz;
    const float ird = sqrtf(irx * irx + iry * iry + irz * irz);
    const float iir = 1.0f / (ird + EPSF);
    const float irnx = irx * iir, irny = iry * iir, irnz = irz * iir;

    const float icx = cx - ix, icy = cy - iy, icz = cz - iz;
    const float icd = sqrtf(icx * icx + icy * icy + icz * icz);
    const float iic = 1.0f / (icd + EPSF);
    const float icnx = icx * iic, icny = icy * iic, icnz = icz * iic;

    const float a_ric = irnx * icnx + irny * icny + irnz * icnz;

    // reference plane normal: cross(r - i, c - r), normalized
    const float e1x = rx - ix, e1y = ry - iy, e1z = rz - iz;
    const float e2x = cx - rx, e2y = cy - ry, e2z = cz - rz;
    float rnx = e1y * e2z - e1z * e2y;
    float rny = e1z * e2x - e1x * e2z;
    float rnz = e1x * e2y - e1y * e2x;
    const float rnl  = sqrtf(rnx * rnx + rny * rny + rnz * rnz);
    const float irnl = 1.0f / (rnl + EPSF);
    rnx *= irnl; rny *= irnl; rnz *= irnl;

    // ---- per-neighbor features ----
    const float ncx = cx - gx, ncy = cy - gy, ncz = cz - gz;
    const float ncd = sqrtf(ncx * ncx + ncy * ncy + ncz * ncz);
    const float inc = 1.0f / (ncd + EPSF);
    const float ncnx = ncx * inc, ncny = ncy * inc, ncnz = ncz * inc;

    const float nrx = rx - gx, nry = ry - gy, nrz = rz - gz;
    const float nrd = sqrtf(nrx * nrx + nry * nry + nrz * nrz);
    const float inr = 1.0f / (nrd + EPSF);
    const float nrnx = nrx * inr, nrny = nry * inr, nrnz = nrz * inr;

    const float nivx = ix - gx, nivy = iy - gy, nivz = iz - gz;
    const float nid = sqrtf(nivx * nivx + nivy * nivy + nivz * nivz);
    const float ini = 1.0f / (nid + EPSF);
    const float ninx = nivx * ini, niny = nivy * ini, ninz = nivz * ini;

    const float ang_cnr = ncnx * nrnx + ncny * nrny + ncnz * nrnz;
    const float ang_rni = nrnx * ninx + nrny * niny + nrnz * ninz;
    const float ang_inc = ninx * ncnx + niny * ncny + ninz * ncnz;

    // neighbor plane normal: cross(r - i, g - r), normalized
    const float f2x = gx - rx, f2y = gy - ry, f2z = gz - rz;
    float qnx = e1y * f2z - e1z * f2y;
    float qny = e1z * f2x - e1x * f2z;
    float qnz = e1x * f2y - e1y * f2x;
    const float qnl = sqrtf(qnx * qnx + qny * qny + qnz * qnz);
    const float iqn = 1.0f / (qnl + EPSF);
    qnx *= iqn; qny *= iqn; qnz *= iqn;

    float dt = rnx * qnx + rny * qny + rnz * qnz;
    dt = fminf(fmaxf(dt, -1.0f), 1.0f);
    // angle = cos(pad/4) - sin(pad/4) - 0.75 via double half-angle (no acosf)
    const float pss = rnx * f2x + rny * f2y + rnz * f2z;   // ref_n . (g - r)
    const float sgn = (pss > 0.0f) ? 1.0f : ((pss < 0.0f) ? -1.0f : 0.0f);
    const float c2  = sqrtf(fmaxf(0.5f * (1.0f + dt), 0.0f));
    const float c4  = sqrtf(fmaxf(0.5f * (1.0f + c2), 0.0f));
    const float s4  = sqrtf(fmaxf(0.5f * (1.0f - c2), 0.0f));
    const float ceff = (sgn == 0.0f) ? 1.0f : c4;          // pad==0 when sign==0
    const float angle = ceff - sgn * s4 - 0.75f;

    // ---- pack the 12 features into 6 f16x2 ----
    F16Pack fp[6];
    fp[0].h[0] = (_Float16)rnorm;   fp[0].h[1] = (_Float16)crd;
    fp[1].h[0] = (_Float16)cid;     fp[1].h[1] = (_Float16)a_rci;
    fp[2].h[0] = (_Float16)a_ric;   fp[2].h[1] = (_Float16)ncd;
    fp[3].h[0] = (_Float16)nrd;     fp[3].h[1] = (_Float16)nid;
    fp[4].h[0] = (_Float16)ang_cnr; fp[4].h[1] = (_Float16)ang_rni;
    fp[5].h[0] = (_Float16)ang_inc; fp[5].h[1] = (_Float16)angle;

    // ---- conv1 12->32 + BN + ReLU via fdot2 (6 per channel) ----
    float h1[32];
#pragma unroll
    for (int o = 0; o < 32; ++o) {
        float a = 0.0f;
#pragma unroll
        for (int k = 0; k < 6; ++k) {
            F16Pack wv; wv.u = wsu[WS_W1 + o * 6 + k];   // uniform -> s_load
            a = __builtin_amdgcn_fdot2(wv.h, fp[k].h, a, false);
        }
        h1[o] = fmaxf(fmaf(a, wsf[WS_S1 + o], wsf[WS_T1 + o]), 0.0f);
    }

    // ---- pack h1 into 16 f16x2 ----
    F16Pack hp[16];
#pragma unroll
    for (int k = 0; k < 16; ++k) {
        hp[k].h[0] = (_Float16)h1[2 * k];
        hp[k].h[1] = (_Float16)h1[2 * k + 1];
    }

    // ---- conv2 32->64 + BN + ReLU via fdot2 + channel-splitting max ----
#pragma unroll
    for (int half = 0; half < 2; ++half) {
        float acc[32];
#pragma unroll
        for (int o = 0; o < 32; ++o) {
            const int oo = half * 32 + o;
            float a = 0.0f;
#pragma unroll
            for (int k = 0; k < 16; ++k) {
                F16Pack wv; wv.u = wsu[WS_W2 + oo * 16 + k];   // uniform -> s_load
                a = __builtin_amdgcn_fdot2(wv.h, hp[k].h, a, false);
            }
            acc[o] = fmaxf(fmaf(a, wsf[WS_S2 + oo], wsf[WS_T2 + oo]), 0.0f);
        }
        rstep<16, 16>(acc, t);
        rstep<8, 8>(acc, t);
        rstep<4, 4>(acc, t);
        rstep<2, 2>(acc, t);
        rstep<1, 1>(acc, t);
        res[half * 32 + t][pt] = acc[0];
    }
    __syncthreads();

    // ---- coalesced-ish output: out[b][o][n], 8 consecutive n per block ----
    const int b  = p0 >> 12;          // / 4096
    const int n0 = p0 & (Nn - 1);
    float* ob = out + (size_t)b * 64 * Nn + n0;
    for (int i2 = tid; i2 < 64 * PPB; i2 += NTHREADS) {
        int o = i2 >> 3, q = i2 & 7;
        ob[(size_t)o * Nn + q] = res[o][q];
    }
}

extern "C" void kernel_launch(void* const* d_in, const int* in_sizes, int n_in,
                              void* d_out, int out_size, void* d_ws, size_t ws_size,
                              hipStream_t stream) {
    const float* xyz  = (const float*)d_in[0];
    const float* mask = (const float*)d_in[1];
    const float* w1   = (const float*)d_in[2];
    const float* g1   = (const float*)d_in[3];
    const float* b1   = (const float*)d_in[4];
    const float* m1   = (const float*)d_in[5];
    const float* v1   = (const float*)d_in[6];
    const float* w2   = (const float*)d_in[7];
    const float* g2   = (const float*)d_in[8];
    const float* b2   = (const float*)d_in[9];
    const float* m2   = (const float*)d_in[10];
    const float* v2   = (const float*)d_in[11];
    float* out = (float*)d_out;
    float* wsf = (float*)d_ws;

    prep<<<1, 256, 0, stream>>>(w1, g1, b1, m1, v1, w2, g2, b2, m2, v2, wsf);
    rri_fused<<<dim3(NPTS / PPB), NTHREADS, 0, stream>>>(xyz, mask, wsf, out);
}